// Round 14
// baseline (560.818 us; speedup 1.0000x reference)
//
#include <hip/hip_runtime.h>

#define NB_MAX 1024       // LDS counter capacity (partition)
#define RA 196            // rows per A-bucket  (256 buckets for V=50000)
#define RX 79             // rows per X-bucket  (254 buckets for D=20000)
#define CAP 8192          // records per bucket slab (mean 6272, sd ~79 -> 24 sd)
#define PT_THREADS 512
#define PT_EPT 32         // 196 partition tiles
#define TILE_EDGES (PT_THREADS * PT_EPT)

// ---- bf16 helpers: table uint at [row][l] packs cols (2l, 2l+1) ------------
__device__ __forceinline__ float blo(unsigned u) { return __uint_as_float(u << 16); }
__device__ __forceinline__ float bhi(unsigned u) { return __uint_as_float(u & 0xffff0000u); }
__device__ __forceinline__ unsigned pack_bf16(float x, float y) {
    unsigned ux = __float_as_uint(x); ux += 0x7fffu + ((ux >> 16) & 1u);
    unsigned uy = __float_as_uint(y); uy += 0x7fffu + ((uy >> 16) & 1u);
    return (ux >> 16) | (uy & 0xffff0000u);
}

// ---------------------------------------------------------------------------
// Merged partition + prep (R13 proven). Partition tiles into fixed-capacity
// bucket slabs (base = b*CAP); prep blocks transpose weights + pack emb bf16.
// Record: x = (row_local << 17) | col, y = bits(val).
// ---------------------------------------------------------------------------
__global__ __launch_bounds__(PT_THREADS) void partprep_kernel(
    const int* __restrict__ Arow, const int* __restrict__ Acol, const float* __restrict__ Aval, int nA,
    const int* __restrict__ Xrow, const int* __restrict__ Xcol, const float* __restrict__ Xval, int nX,
    int nbA, int nb, int ptBlocks, int* __restrict__ gcur, uint2* __restrict__ ebuf,
    const float* __restrict__ W1, const float* __restrict__ W2, const float* __restrict__ W3,
    float* __restrict__ Wt1, float* __restrict__ Wt2, float* __restrict__ Wt3,
    const float2* __restrict__ emb, unsigned* __restrict__ emb16, int nemb) {

    if (blockIdx.x >= ptBlocks) {
        int gid = (blockIdx.x - ptBlocks) * PT_THREADS + threadIdx.x;
        if (gid < 3 * 16384) {
            int m = gid >> 14;
            int idx = gid & 16383;
            int j = idx >> 7;
            int k = idx & 127;
            const float* W = (m == 0) ? W1 : (m == 1) ? W2 : W3;
            float*      Wt = (m == 0) ? Wt1 : (m == 1) ? Wt2 : Wt3;
            Wt[k * 128 + j] = W[j * 128 + k];
        }
        int e = gid - 3 * 16384;
        if (e >= 0 && e < nemb) {
            float2 f = emb[e];
            emb16[e] = pack_bf16(f.x, f.y);
        }
        return;
    }

    __shared__ int cnt[NB_MAX];
    __shared__ int rbase[NB_MAX];
    for (int t = threadIdx.x; t < nb; t += PT_THREADS) cnt[t] = 0;
    __syncthreads();
    int tot = nA + nX;
    int t0 = blockIdx.x * TILE_EDGES;
    #pragma unroll 4
    for (int k = 0; k < PT_EPT; ++k) {
        int i = t0 + k * PT_THREADS + threadIdx.x;
        if (i < tot) {
            int b = (i < nA) ? (Arow[i] / RA) : (nbA + Xrow[i - nA] / RX);
            atomicAdd(&cnt[b], 1);
        }
    }
    __syncthreads();
    for (int t = threadIdx.x; t < nb; t += PT_THREADS) {
        int c = cnt[t];
        rbase[t] = t * CAP + (c ? atomicAdd(&gcur[t], c) : 0);
        cnt[t] = 0;
    }
    __syncthreads();
    #pragma unroll 4
    for (int k = 0; k < PT_EPT; ++k) {
        int i = t0 + k * PT_THREADS + threadIdx.x;
        if (i < tot) {
            int b, rl, col; float val;
            if (i < nA) {
                int r = Arow[i]; b = r / RA; rl = r - b * RA;
                col = Acol[i]; val = Aval[i];
            } else {
                int j = i - nA; int r = Xrow[j]; int bx = r / RX;
                b = nbA + bx; rl = r - bx * RX;
                col = Xcol[j]; val = Xval[j];
            }
            int pos = rbase[b] + atomicAdd(&cnt[b], 1);
            ebuf[pos] = make_uint2(((unsigned)rl << 17) | (unsigned)col, __float_as_uint(val));
        }
    }
}

// ---------------------------------------------------------------------------
// Cluster (register-cached): one block per bucket. Records (<= CAP = 8*1024)
// are loaded ONCE into registers (8 uint2/thread), histogrammed, scanned,
// and scattered from registers — deletes the second 26 MB ebuf read pass.
// ---------------------------------------------------------------------------
__global__ __launch_bounds__(1024) void cluster2_kernel(
    const uint2* __restrict__ ebuf, const int* __restrict__ gcur,
    int* __restrict__ rsA, int* __restrict__ reA,
    int* __restrict__ rsX, int* __restrict__ reX,
    int2* __restrict__ csrA, int2* __restrict__ csrX,
    int nbA, int V, int D) {
    __shared__ int rcnt[RA + 1];
    __shared__ int lcur[RA];
    int b = blockIdx.x;
    int r0, rows; int* rs; int* re; int2* csr; int slot;
    if (b < nbA) {
        r0 = b * RA; rows = min(V - r0, RA);
        rs = rsA; re = reA; csr = csrA; slot = b;
    } else {
        int j = b - nbA;
        r0 = j * RX; rows = min(D - r0, RX);
        rs = rsX; re = reX; csr = csrX; slot = j;
    }
    int s = b * CAP;
    int cnt = gcur[b];
    int base = slot * CAP;

    // load this thread's records once
    uint2 rec[8];
    int nrec = 0;
    #pragma unroll
    for (int k = 0; k < 8; ++k) {
        int i = k * 1024 + threadIdx.x;
        if (i < cnt) { rec[k] = ebuf[s + i]; nrec = k + 1; }
    }

    for (int t = threadIdx.x; t <= rows; t += 1024) rcnt[t] = 0;
    __syncthreads();
    #pragma unroll
    for (int k = 0; k < 8; ++k)
        if (k < nrec) atomicAdd(&rcnt[rec[k].x >> 17], 1);
    __syncthreads();

    if (threadIdx.x < 64) {
        int lane = threadIdx.x;
        int carry = 0;
        for (int sb = 0; sb < rows; sb += 64) {
            int idx = sb + lane;
            int v = (idx < rows) ? rcnt[idx] : 0;
            int incl = v;
            #pragma unroll
            for (int d = 1; d < 64; d <<= 1) {
                int t = __shfl_up(incl, d);
                if (lane >= d) incl += t;
            }
            int tot = __shfl(incl, 63);
            if (idx < rows) rcnt[idx] = carry + incl - v;
            carry += tot;
        }
        if (lane == 0) rcnt[rows] = carry;
    }
    __syncthreads();

    for (int t = threadIdx.x; t < rows; t += 1024) {
        rs[r0 + t] = base + rcnt[t];
        re[r0 + t] = base + rcnt[t + 1];
        lcur[t] = rcnt[t];
    }
    __syncthreads();

    #pragma unroll
    for (int k = 0; k < 8; ++k) {
        if (k < nrec) {
            int rl = rec[k].x >> 17;
            int p = base + atomicAdd(&lcur[rl], 1);
            csr[p] = make_int2(rec[k].x & 0x1FFFF, (int)rec[k].y);
        }
    }
}

// ---------------------------------------------------------------------------
// SpMM row gather-reduce (R10/R12 proven form): 16-batch, 8-batch, scalar tail.
// ---------------------------------------------------------------------------
__device__ __forceinline__ void spmm_row16(const int2* __restrict__ csr, int s, int e,
                                           const unsigned* __restrict__ in, int lane,
                                           float& ax, float& ay) {
    int i = s;
    #pragma unroll 1
    for (; i + 15 < e; i += 16) {
        int2 c[16];
        #pragma unroll
        for (int k = 0; k < 16; ++k) c[k] = csr[i + k];
        unsigned x[16];
        #pragma unroll
        for (int k = 0; k < 16; ++k) x[k] = in[(size_t)c[k].x * 64 + lane];
        #pragma unroll
        for (int k = 0; k < 16; ++k) {
            float v = __int_as_float(c[k].y);
            ax += v * blo(x[k]);
            ay += v * bhi(x[k]);
        }
    }
    #pragma unroll 1
    for (; i + 7 < e; i += 8) {
        int2 c[8];
        #pragma unroll
        for (int k = 0; k < 8; ++k) c[k] = csr[i + k];
        unsigned x[8];
        #pragma unroll
        for (int k = 0; k < 8; ++k) x[k] = in[(size_t)c[k].x * 64 + lane];
        #pragma unroll
        for (int k = 0; k < 8; ++k) {
            float v = __int_as_float(c[k].y);
            ax += v * blo(x[k]);
            ay += v * bhi(x[k]);
        }
    }
    #pragma unroll 1
    for (; i < e; ++i) {
        int2 cv = csr[i];
        unsigned x = in[(size_t)cv.x * 64 + lane];
        float v = __int_as_float(cv.y);
        ax += v * blo(x);
        ay += v * bhi(x);
    }
}

// ---------------------------------------------------------------------------
// Fused layer kernel. R=2: grid 782 -> 1563 blocks (3 -> 6.1/CU). Occupancy
// was grid-limited at 57% (VGPR 36 / LDS 16K nowhere near caps); more resident
// waves = more outstanding gathers. Weight re-reads double but Wt is a 64 KB
// L1/L2-resident table — nearly free.
//   mode 0: out = bf16(relu(spmm(A,in) @ W^T))
//   mode 1: t = relu(spmm(A,in) @ W^T); u = 0.3*emb + 0.7*t;
//           out = bf16(layernorm(u)*g + b + emb)   (word_H + emb_W pre-fused)
// ---------------------------------------------------------------------------
template <int R>
__global__ __launch_bounds__(256, 6) void layer_kernel(
    const int* __restrict__ rs, const int* __restrict__ re,
    const int2* __restrict__ csr,
    const unsigned* __restrict__ in,          // bf16-packed [nrows][64]
    const float2* __restrict__ Wt,            // [128][64] float2 view
    const float2* __restrict__ emb,           // fp32, mode 1 only
    const float* __restrict__ g, const float* __restrict__ bb,  // mode 1 only
    unsigned* __restrict__ out, int nrows, int mode) {

    __shared__ float acc_s[4][R][128];
    int lane = threadIdx.x & 63;
    int wave = threadIdx.x >> 6;
    int rowbase = (blockIdx.x * 4 + wave) * R;

    #pragma unroll 1
    for (int r = 0; r < R; ++r) {
        int row = rowbase + r;
        float ax = 0.f, ay = 0.f;
        if (row < nrows) {
            spmm_row16(csr, rs[row], re[row], in, lane, ax, ay);
        }
        *(float2*)&acc_s[wave][r][2 * lane] = make_float2(ax, ay);
    }

    float2 o[R];
    #pragma unroll
    for (int r = 0; r < R; ++r) o[r] = make_float2(0.f, 0.f);
    #pragma unroll 4
    for (int k = 0; k < 128; k += 2) {
        float2 w0 = Wt[(size_t)k * 64 + lane];
        float2 w1 = Wt[(size_t)(k + 1) * 64 + lane];
        #pragma unroll
        for (int r = 0; r < R; ++r) {
            float b0 = acc_s[wave][r][k];
            float b1 = acc_s[wave][r][k + 1];
            o[r].x += b0 * w0.x + b1 * w1.x;
            o[r].y += b0 * w0.y + b1 * w1.y;
        }
    }

    #pragma unroll 1
    for (int r = 0; r < R; ++r) {
        int row = rowbase + r;
        if (row >= nrows) break;
        float hx = fmaxf(o[r].x, 0.f), hy = fmaxf(o[r].y, 0.f);
        if (mode == 0) {
            out[(size_t)row * 64 + lane] = pack_bf16(hx, hy);
        } else {
            float2 e2 = emb[(size_t)row * 64 + lane];
            float ux = 0.3f * e2.x + 0.7f * hx;
            float uy = 0.3f * e2.y + 0.7f * hy;
            float s = ux + uy;
            #pragma unroll
            for (int d = 1; d < 64; d <<= 1) s += __shfl_xor(s, d);
            float mu = s * (1.f / 128.f);
            float dx = ux - mu, dy = uy - mu;
            float qv = dx * dx + dy * dy;
            #pragma unroll
            for (int d = 1; d < 64; d <<= 1) qv += __shfl_xor(qv, d);
            float rstd = rsqrtf(qv * (1.f / 128.f) + 1e-5f);
            float2 gg = *(const float2*)&g[2 * lane];
            float2 b2 = *(const float2*)&bb[2 * lane];
            float wx = dx * rstd * gg.x + b2.x + e2.x;   // word_H + emb_W fused
            float wy = dy * rstd * gg.y + b2.y + e2.y;
            out[(size_t)row * 64 + lane] = pack_bf16(wx, wy);
        }
    }
}

// ---------------------------------------------------------------------------
// Doc kernel: spmm(X, word_sum[bf16]) -> relu(. @ mlp_W^T + b) -> clf logits.
// ---------------------------------------------------------------------------
template <int R>
__global__ __launch_bounds__(256, 6) void doc_kernel(
    const int* __restrict__ rs, const int* __restrict__ re,
    const int2* __restrict__ csr,
    const unsigned* __restrict__ in,          // bf16-packed word_sum [V][64]
    const float2* __restrict__ Wt,            // mlp_W transposed, float2 view
    const float* __restrict__ mlp_b, const float* __restrict__ clfW,
    const float* __restrict__ clfb,
    float* __restrict__ outp, int nrows) {

    __shared__ float acc_s[4][R][128];
    int lane = threadIdx.x & 63;
    int wave = threadIdx.x >> 6;
    int rowbase = (blockIdx.x * 4 + wave) * R;

    #pragma unroll 1
    for (int r = 0; r < R; ++r) {
        int row = rowbase + r;
        float ax = 0.f, ay = 0.f;
        if (row < nrows) {
            spmm_row16(csr, rs[row], re[row], in, lane, ax, ay);
        }
        *(float2*)&acc_s[wave][r][2 * lane] = make_float2(ax, ay);
    }

    float2 o[R];
    #pragma unroll
    for (int r = 0; r < R; ++r) o[r] = make_float2(0.f, 0.f);
    #pragma unroll 4
    for (int k = 0; k < 128; k += 2) {
        float2 w0 = Wt[(size_t)k * 64 + lane];
        float2 w1 = Wt[(size_t)(k + 1) * 64 + lane];
        #pragma unroll
        for (int r = 0; r < R; ++r) {
            float b0 = acc_s[wave][r][k];
            float b1 = acc_s[wave][r][k + 1];
            o[r].x += b0 * w0.x + b1 * w1.x;
            o[r].y += b0 * w0.y + b1 * w1.y;
        }
    }

    float2 mb = *(const float2*)&mlp_b[2 * lane];
    float2 c0 = *(const float2*)&clfW[2 * lane];
    float2 c1 = *(const float2*)&clfW[128 + 2 * lane];
    #pragma unroll 1
    for (int r = 0; r < R; ++r) {
        int row = rowbase + r;
        if (row >= nrows) break;
        float hx = fmaxf(o[r].x + mb.x, 0.f);
        float hy = fmaxf(o[r].y + mb.y, 0.f);
        float p0 = hx * c0.x + hy * c0.y;
        float p1 = hx * c1.x + hy * c1.y;
        #pragma unroll
        for (int d = 1; d < 64; d <<= 1) {
            p0 += __shfl_xor(p0, d);
            p1 += __shfl_xor(p1, d);
        }
        if (lane == 0) {
            outp[(size_t)row * 2 + 0] = p0 + clfb[0];
            outp[(size_t)row * 2 + 1] = p1 + clfb[1];
        }
    }
}

// ---------------------------------------------------------------------------
extern "C" void kernel_launch(void* const* d_in, const int* in_sizes, int n_in,
                              void* d_out, int out_size, void* d_ws, size_t ws_size,
                              hipStream_t stream) {
    const int*   A_row  = (const int*)d_in[0];
    const int*   A_col  = (const int*)d_in[1];
    const float* A_val  = (const float*)d_in[2];
    const int*   X_row  = (const int*)d_in[3];
    const int*   X_col  = (const int*)d_in[4];
    const float* X_val  = (const float*)d_in[5];
    const float* emb_W  = (const float*)d_in[6];
    const float* lin1_W = (const float*)d_in[7];
    const float* lin2_W = (const float*)d_in[8];
    const float* norm_g = (const float*)d_in[9];
    const float* norm_b = (const float*)d_in[10];
    const float* mlp_W  = (const float*)d_in[11];
    const float* mlp_b  = (const float*)d_in[12];
    const float* clf_W  = (const float*)d_in[13];
    const float* clf_b  = (const float*)d_in[14];

    const int E   = in_sizes[0];
    const int NNZ = in_sizes[3];
    const int V   = in_sizes[6] / 128;
    const int D   = out_size / 2;   // N_DOCS
    const int tot = E + NNZ;
    const int nbA = (V + RA - 1) / RA;   // 256
    const int nbX = (D + RX - 1) / RX;   // 254
    const int nb  = nbA + nbX;           // 510 <= NB_MAX

    // workspace carve-up (256B aligned)
    char* p = (char*)d_ws;
    auto alloc = [&](size_t bytes) -> void* {
        void* q = (void*)p;
        p += (bytes + 255) & ~(size_t)255;
        return q;
    };
    int*      rsA   = (int*)alloc((size_t)V * 4);
    int*      reA   = (int*)alloc((size_t)V * 4);
    int*      rsX   = (int*)alloc((size_t)D * 4);
    int*      reX   = (int*)alloc((size_t)D * 4);
    int*      gcur  = (int*)alloc((size_t)nb * 4);
    int2*     csrA  = (int2*)alloc((size_t)nbA * CAP * 8);
    int2*     csrX  = (int2*)alloc((size_t)nbX * CAP * 8);
    float*    Wt1   = (float*)alloc(128 * 128 * 4);
    float*    Wt2   = (float*)alloc(128 * 128 * 4);
    float*    Wt3   = (float*)alloc(128 * 128 * 4);
    unsigned* P_EMB = (unsigned*)alloc((size_t)V * 64 * 4);
    // ebuf (bucket slabs) is dead after cluster2; H1/WS alias it.
    size_t ebuf_bytes = (size_t)nb * CAP * 8;
    size_t hw_bytes   = 2 * (size_t)V * 64 * 4;
    char*     ebuf_region = (char*)alloc(ebuf_bytes > hw_bytes ? ebuf_bytes : hw_bytes);
    uint2*    ebuf  = (uint2*)ebuf_region;
    unsigned* P_H1  = (unsigned*)ebuf_region;
    unsigned* P_WS  = (unsigned*)(ebuf_region + (size_t)V * 64 * 4);

    hipMemsetAsync(gcur, 0, (size_t)nb * 4, stream);

    const int ptBlocks = (tot + TILE_EDGES - 1) / TILE_EDGES;              // 196
    const int prepBlocks = (3 * 16384 + V * 64 + PT_THREADS - 1) / PT_THREADS;
    partprep_kernel<<<ptBlocks + prepBlocks, PT_THREADS, 0, stream>>>(
        A_row, A_col, A_val, E, X_row, X_col, X_val, NNZ,
        nbA, nb, ptBlocks, gcur, ebuf,
        lin1_W, lin2_W, mlp_W, Wt1, Wt2, Wt3,
        (const float2*)emb_W, P_EMB, V * 64);
    cluster2_kernel<<<nb, 1024, 0, stream>>>(
        ebuf, gcur, rsA, reA, rsX, reX, csrA, csrX, nbA, V, D);

    int layer_blocks = (V + 4 * 2 - 1) / (4 * 2);
    layer_kernel<2><<<layer_blocks, 256, 0, stream>>>(
        rsA, reA, csrA, P_EMB, (const float2*)Wt1,
        nullptr, nullptr, nullptr, P_H1, V, 0);
    layer_kernel<2><<<layer_blocks, 256, 0, stream>>>(
        rsA, reA, csrA, P_H1, (const float2*)Wt2,
        (const float2*)emb_W, norm_g, norm_b, P_WS, V, 1);

    int doc_blocks = (D + 4 * 2 - 1) / (4 * 2);
    doc_kernel<2><<<doc_blocks, 256, 0, stream>>>(
        rsX, reX, csrX, P_WS, (const float2*)Wt3,
        mlp_b, clf_W, clf_b, (float*)d_out, D);
}

// Round 15
// 464.874 us; speedup vs baseline: 1.2064x; 1.2064x over previous
//
#include <hip/hip_runtime.h>

#define NB_MAX 1024       // LDS counter capacity (partition)
#define RA 196            // rows per A-bucket  (256 buckets for V=50000)
#define RX 79             // rows per X-bucket  (254 buckets for D=20000)
#define CAP 8192          // records per bucket slab (mean 6272, sd ~79 -> 24 sd)
#define PT_THREADS 512
#define PT_EPT 32         // 196 partition tiles
#define TILE_EDGES (PT_THREADS * PT_EPT)

// ---- bf16 helpers: table uint at [row][l] packs cols (2l, 2l+1) ------------
__device__ __forceinline__ float blo(unsigned u) { return __uint_as_float(u << 16); }
__device__ __forceinline__ float bhi(unsigned u) { return __uint_as_float(u & 0xffff0000u); }
__device__ __forceinline__ unsigned pack_bf16(float x, float y) {
    unsigned ux = __float_as_uint(x); ux += 0x7fffu + ((ux >> 16) & 1u);
    unsigned uy = __float_as_uint(y); uy += 0x7fffu + ((uy >> 16) & 1u);
    return (ux >> 16) | (uy & 0xffff0000u);
}

// ---------------------------------------------------------------------------
// Merged partition + prep (R13 proven). Partition tiles into fixed-capacity
// bucket slabs (base = b*CAP); prep blocks transpose weights + pack emb bf16.
// Record: x = (row_local << 17) | col, y = bits(val).
// ---------------------------------------------------------------------------
__global__ __launch_bounds__(PT_THREADS) void partprep_kernel(
    const int* __restrict__ Arow, const int* __restrict__ Acol, const float* __restrict__ Aval, int nA,
    const int* __restrict__ Xrow, const int* __restrict__ Xcol, const float* __restrict__ Xval, int nX,
    int nbA, int nb, int ptBlocks, int* __restrict__ gcur, uint2* __restrict__ ebuf,
    const float* __restrict__ W1, const float* __restrict__ W2, const float* __restrict__ W3,
    float* __restrict__ Wt1, float* __restrict__ Wt2, float* __restrict__ Wt3,
    const float2* __restrict__ emb, unsigned* __restrict__ emb16, int nemb) {

    if (blockIdx.x >= ptBlocks) {
        int gid = (blockIdx.x - ptBlocks) * PT_THREADS + threadIdx.x;
        if (gid < 3 * 16384) {
            int m = gid >> 14;
            int idx = gid & 16383;
            int j = idx >> 7;
            int k = idx & 127;
            const float* W = (m == 0) ? W1 : (m == 1) ? W2 : W3;
            float*      Wt = (m == 0) ? Wt1 : (m == 1) ? Wt2 : Wt3;
            Wt[k * 128 + j] = W[j * 128 + k];
        }
        int e = gid - 3 * 16384;
        if (e >= 0 && e < nemb) {
            float2 f = emb[e];
            emb16[e] = pack_bf16(f.x, f.y);
        }
        return;
    }

    __shared__ int cnt[NB_MAX];
    __shared__ int rbase[NB_MAX];
    for (int t = threadIdx.x; t < nb; t += PT_THREADS) cnt[t] = 0;
    __syncthreads();
    int tot = nA + nX;
    int t0 = blockIdx.x * TILE_EDGES;
    #pragma unroll 4
    for (int k = 0; k < PT_EPT; ++k) {
        int i = t0 + k * PT_THREADS + threadIdx.x;
        if (i < tot) {
            int b = (i < nA) ? (Arow[i] / RA) : (nbA + Xrow[i - nA] / RX);
            atomicAdd(&cnt[b], 1);
        }
    }
    __syncthreads();
    for (int t = threadIdx.x; t < nb; t += PT_THREADS) {
        int c = cnt[t];
        rbase[t] = t * CAP + (c ? atomicAdd(&gcur[t], c) : 0);
        cnt[t] = 0;
    }
    __syncthreads();
    #pragma unroll 4
    for (int k = 0; k < PT_EPT; ++k) {
        int i = t0 + k * PT_THREADS + threadIdx.x;
        if (i < tot) {
            int b, rl, col; float val;
            if (i < nA) {
                int r = Arow[i]; b = r / RA; rl = r - b * RA;
                col = Acol[i]; val = Aval[i];
            } else {
                int j = i - nA; int r = Xrow[j]; int bx = r / RX;
                b = nbA + bx; rl = r - bx * RX;
                col = Xcol[j]; val = Xval[j];
            }
            int pos = rbase[b] + atomicAdd(&cnt[b], 1);
            ebuf[pos] = make_uint2(((unsigned)rl << 17) | (unsigned)col, __float_as_uint(val));
        }
    }
}

// ---------------------------------------------------------------------------
// Cluster (register-cached, R14's one clean win): one block per bucket.
// Records (<= CAP = 8*1024) load ONCE into registers (8 uint2/thread),
// histogram, scan, scatter from registers — no second ebuf read pass.
// ---------------------------------------------------------------------------
__global__ __launch_bounds__(1024) void cluster2_kernel(
    const uint2* __restrict__ ebuf, const int* __restrict__ gcur,
    int* __restrict__ rsA, int* __restrict__ reA,
    int* __restrict__ rsX, int* __restrict__ reX,
    int2* __restrict__ csrA, int2* __restrict__ csrX,
    int nbA, int V, int D) {
    __shared__ int rcnt[RA + 1];
    __shared__ int lcur[RA];
    int b = blockIdx.x;
    int r0, rows; int* rs; int* re; int2* csr; int slot;
    if (b < nbA) {
        r0 = b * RA; rows = min(V - r0, RA);
        rs = rsA; re = reA; csr = csrA; slot = b;
    } else {
        int j = b - nbA;
        r0 = j * RX; rows = min(D - r0, RX);
        rs = rsX; re = reX; csr = csrX; slot = j;
    }
    int s = b * CAP;
    int cnt = gcur[b];
    int base = slot * CAP;

    uint2 rec[8];
    int nrec = 0;
    #pragma unroll
    for (int k = 0; k < 8; ++k) {
        int i = k * 1024 + threadIdx.x;
        if (i < cnt) { rec[k] = ebuf[s + i]; nrec = k + 1; }
    }

    for (int t = threadIdx.x; t <= rows; t += 1024) rcnt[t] = 0;
    __syncthreads();
    #pragma unroll
    for (int k = 0; k < 8; ++k)
        if (k < nrec) atomicAdd(&rcnt[rec[k].x >> 17], 1);
    __syncthreads();

    if (threadIdx.x < 64) {
        int lane = threadIdx.x;
        int carry = 0;
        for (int sb = 0; sb < rows; sb += 64) {
            int idx = sb + lane;
            int v = (idx < rows) ? rcnt[idx] : 0;
            int incl = v;
            #pragma unroll
            for (int d = 1; d < 64; d <<= 1) {
                int t = __shfl_up(incl, d);
                if (lane >= d) incl += t;
            }
            int tot = __shfl(incl, 63);
            if (idx < rows) rcnt[idx] = carry + incl - v;
            carry += tot;
        }
        if (lane == 0) rcnt[rows] = carry;
    }
    __syncthreads();

    for (int t = threadIdx.x; t < rows; t += 1024) {
        rs[r0 + t] = base + rcnt[t];
        re[r0 + t] = base + rcnt[t + 1];
        lcur[t] = rcnt[t];
    }
    __syncthreads();

    #pragma unroll
    for (int k = 0; k < 8; ++k) {
        if (k < nrec) {
            int rl = rec[k].x >> 17;
            int p = base + atomicAdd(&lcur[rl], 1);
            csr[p] = make_int2(rec[k].x & 0x1FFFF, (int)rec[k].y);
        }
    }
}

// ---------------------------------------------------------------------------
// SpMM row gather-reduce (R10/R12/R13 proven): 16-batch, 8-batch, scalar tail.
// ---------------------------------------------------------------------------
__device__ __forceinline__ void spmm_row16(const int2* __restrict__ csr, int s, int e,
                                           const unsigned* __restrict__ in, int lane,
                                           float& ax, float& ay) {
    int i = s;
    #pragma unroll 1
    for (; i + 15 < e; i += 16) {
        int2 c[16];
        #pragma unroll
        for (int k = 0; k < 16; ++k) c[k] = csr[i + k];
        unsigned x[16];
        #pragma unroll
        for (int k = 0; k < 16; ++k) x[k] = in[(size_t)c[k].x * 64 + lane];
        #pragma unroll
        for (int k = 0; k < 16; ++k) {
            float v = __int_as_float(c[k].y);
            ax += v * blo(x[k]);
            ay += v * bhi(x[k]);
        }
    }
    #pragma unroll 1
    for (; i + 7 < e; i += 8) {
        int2 c[8];
        #pragma unroll
        for (int k = 0; k < 8; ++k) c[k] = csr[i + k];
        unsigned x[8];
        #pragma unroll
        for (int k = 0; k < 8; ++k) x[k] = in[(size_t)c[k].x * 64 + lane];
        #pragma unroll
        for (int k = 0; k < 8; ++k) {
            float v = __int_as_float(c[k].y);
            ax += v * blo(x[k]);
            ay += v * bhi(x[k]);
        }
    }
    #pragma unroll 1
    for (; i < e; ++i) {
        int2 cv = csr[i];
        unsigned x = in[(size_t)cv.x * 64 + lane];
        float v = __int_as_float(cv.y);
        ax += v * blo(x);
        ay += v * bhi(x);
    }
}

// ---------------------------------------------------------------------------
// Fused layer kernel. R=4 (R13 proven: R=2 regressed — the 128-float2 Wt
// stream is per-wave fixed cost, halving R doubles per-row GEMM overhead;
// the gather plateau is a chip line-rate limit, not occupancy-starved).
//   mode 0: out = bf16(relu(spmm(A,in) @ W^T))
//   mode 1: t = relu(spmm(A,in) @ W^T); u = 0.3*emb + 0.7*t;
//           out = bf16(layernorm(u)*g + b + emb)   (word_H + emb_W pre-fused)
// ---------------------------------------------------------------------------
template <int R>
__global__ __launch_bounds__(256, 6) void layer_kernel(
    const int* __restrict__ rs, const int* __restrict__ re,
    const int2* __restrict__ csr,
    const unsigned* __restrict__ in,          // bf16-packed [nrows][64]
    const float2* __restrict__ Wt,            // [128][64] float2 view
    const float2* __restrict__ emb,           // fp32, mode 1 only
    const float* __restrict__ g, const float* __restrict__ bb,  // mode 1 only
    unsigned* __restrict__ out, int nrows, int mode) {

    __shared__ float acc_s[4][R][128];
    int lane = threadIdx.x & 63;
    int wave = threadIdx.x >> 6;
    int rowbase = (blockIdx.x * 4 + wave) * R;

    #pragma unroll 1
    for (int r = 0; r < R; ++r) {
        int row = rowbase + r;
        float ax = 0.f, ay = 0.f;
        if (row < nrows) {
            spmm_row16(csr, rs[row], re[row], in, lane, ax, ay);
        }
        *(float2*)&acc_s[wave][r][2 * lane] = make_float2(ax, ay);
    }

    float2 o[R];
    #pragma unroll
    for (int r = 0; r < R; ++r) o[r] = make_float2(0.f, 0.f);
    #pragma unroll 4
    for (int k = 0; k < 128; k += 2) {
        float2 w0 = Wt[(size_t)k * 64 + lane];
        float2 w1 = Wt[(size_t)(k + 1) * 64 + lane];
        #pragma unroll
        for (int r = 0; r < R; ++r) {
            float b0 = acc_s[wave][r][k];
            float b1 = acc_s[wave][r][k + 1];
            o[r].x += b0 * w0.x + b1 * w1.x;
            o[r].y += b0 * w0.y + b1 * w1.y;
        }
    }

    #pragma unroll 1
    for (int r = 0; r < R; ++r) {
        int row = rowbase + r;
        if (row >= nrows) break;
        float hx = fmaxf(o[r].x, 0.f), hy = fmaxf(o[r].y, 0.f);
        if (mode == 0) {
            out[(size_t)row * 64 + lane] = pack_bf16(hx, hy);
        } else {
            float2 e2 = emb[(size_t)row * 64 + lane];
            float ux = 0.3f * e2.x + 0.7f * hx;
            float uy = 0.3f * e2.y + 0.7f * hy;
            float s = ux + uy;
            #pragma unroll
            for (int d = 1; d < 64; d <<= 1) s += __shfl_xor(s, d);
            float mu = s * (1.f / 128.f);
            float dx = ux - mu, dy = uy - mu;
            float qv = dx * dx + dy * dy;
            #pragma unroll
            for (int d = 1; d < 64; d <<= 1) qv += __shfl_xor(qv, d);
            float rstd = rsqrtf(qv * (1.f / 128.f) + 1e-5f);
            float2 gg = *(const float2*)&g[2 * lane];
            float2 b2 = *(const float2*)&bb[2 * lane];
            float wx = dx * rstd * gg.x + b2.x + e2.x;   // word_H + emb_W fused
            float wy = dy * rstd * gg.y + b2.y + e2.y;
            out[(size_t)row * 64 + lane] = pack_bf16(wx, wy);
        }
    }
}

// ---------------------------------------------------------------------------
// Doc kernel: spmm(X, word_sum[bf16]) -> relu(. @ mlp_W^T + b) -> clf logits.
// ---------------------------------------------------------------------------
template <int R>
__global__ __launch_bounds__(256, 6) void doc_kernel(
    const int* __restrict__ rs, const int* __restrict__ re,
    const int2* __restrict__ csr,
    const unsigned* __restrict__ in,          // bf16-packed word_sum [V][64]
    const float2* __restrict__ Wt,            // mlp_W transposed, float2 view
    const float* __restrict__ mlp_b, const float* __restrict__ clfW,
    const float* __restrict__ clfb,
    float* __restrict__ outp, int nrows) {

    __shared__ float acc_s[4][R][128];
    int lane = threadIdx.x & 63;
    int wave = threadIdx.x >> 6;
    int rowbase = (blockIdx.x * 4 + wave) * R;

    #pragma unroll 1
    for (int r = 0; r < R; ++r) {
        int row = rowbase + r;
        float ax = 0.f, ay = 0.f;
        if (row < nrows) {
            spmm_row16(csr, rs[row], re[row], in, lane, ax, ay);
        }
        *(float2*)&acc_s[wave][r][2 * lane] = make_float2(ax, ay);
    }

    float2 o[R];
    #pragma unroll
    for (int r = 0; r < R; ++r) o[r] = make_float2(0.f, 0.f);
    #pragma unroll 4
    for (int k = 0; k < 128; k += 2) {
        float2 w0 = Wt[(size_t)k * 64 + lane];
        float2 w1 = Wt[(size_t)(k + 1) * 64 + lane];
        #pragma unroll
        for (int r = 0; r < R; ++r) {
            float b0 = acc_s[wave][r][k];
            float b1 = acc_s[wave][r][k + 1];
            o[r].x += b0 * w0.x + b1 * w1.x;
            o[r].y += b0 * w0.y + b1 * w1.y;
        }
    }

    float2 mb = *(const float2*)&mlp_b[2 * lane];
    float2 c0 = *(const float2*)&clfW[2 * lane];
    float2 c1 = *(const float2*)&clfW[128 + 2 * lane];
    #pragma unroll 1
    for (int r = 0; r < R; ++r) {
        int row = rowbase + r;
        if (row >= nrows) break;
        float hx = fmaxf(o[r].x + mb.x, 0.f);
        float hy = fmaxf(o[r].y + mb.y, 0.f);
        float p0 = hx * c0.x + hy * c0.y;
        float p1 = hx * c1.x + hy * c1.y;
        #pragma unroll
        for (int d = 1; d < 64; d <<= 1) {
            p0 += __shfl_xor(p0, d);
            p1 += __shfl_xor(p1, d);
        }
        if (lane == 0) {
            outp[(size_t)row * 2 + 0] = p0 + clfb[0];
            outp[(size_t)row * 2 + 1] = p1 + clfb[1];
        }
    }
}

// ---------------------------------------------------------------------------
extern "C" void kernel_launch(void* const* d_in, const int* in_sizes, int n_in,
                              void* d_out, int out_size, void* d_ws, size_t ws_size,
                              hipStream_t stream) {
    const int*   A_row  = (const int*)d_in[0];
    const int*   A_col  = (const int*)d_in[1];
    const float* A_val  = (const float*)d_in[2];
    const int*   X_row  = (const int*)d_in[3];
    const int*   X_col  = (const int*)d_in[4];
    const float* X_val  = (const float*)d_in[5];
    const float* emb_W  = (const float*)d_in[6];
    const float* lin1_W = (const float*)d_in[7];
    const float* lin2_W = (const float*)d_in[8];
    const float* norm_g = (const float*)d_in[9];
    const float* norm_b = (const float*)d_in[10];
    const float* mlp_W  = (const float*)d_in[11];
    const float* mlp_b  = (const float*)d_in[12];
    const float* clf_W  = (const float*)d_in[13];
    const float* clf_b  = (const float*)d_in[14];

    const int E   = in_sizes[0];
    const int NNZ = in_sizes[3];
    const int V   = in_sizes[6] / 128;
    const int D   = out_size / 2;   // N_DOCS
    const int tot = E + NNZ;
    const int nbA = (V + RA - 1) / RA;   // 256
    const int nbX = (D + RX - 1) / RX;   // 254
    const int nb  = nbA + nbX;           // 510 <= NB_MAX

    // workspace carve-up (256B aligned)
    char* p = (char*)d_ws;
    auto alloc = [&](size_t bytes) -> void* {
        void* q = (void*)p;
        p += (bytes + 255) & ~(size_t)255;
        return q;
    };
    int*      rsA   = (int*)alloc((size_t)V * 4);
    int*      reA   = (int*)alloc((size_t)V * 4);
    int*      rsX   = (int*)alloc((size_t)D * 4);
    int*      reX   = (int*)alloc((size_t)D * 4);
    int*      gcur  = (int*)alloc((size_t)nb * 4);
    int2*     csrA  = (int2*)alloc((size_t)nbA * CAP * 8);
    int2*     csrX  = (int2*)alloc((size_t)nbX * CAP * 8);
    float*    Wt1   = (float*)alloc(128 * 128 * 4);
    float*    Wt2   = (float*)alloc(128 * 128 * 4);
    float*    Wt3   = (float*)alloc(128 * 128 * 4);
    unsigned* P_EMB = (unsigned*)alloc((size_t)V * 64 * 4);
    // ebuf (bucket slabs) is dead after cluster2; H1/WS alias it.
    size_t ebuf_bytes = (size_t)nb * CAP * 8;
    size_t hw_bytes   = 2 * (size_t)V * 64 * 4;
    char*     ebuf_region = (char*)alloc(ebuf_bytes > hw_bytes ? ebuf_bytes : hw_bytes);
    uint2*    ebuf  = (uint2*)ebuf_region;
    unsigned* P_H1  = (unsigned*)ebuf_region;
    unsigned* P_WS  = (unsigned*)(ebuf_region + (size_t)V * 64 * 4);

    hipMemsetAsync(gcur, 0, (size_t)nb * 4, stream);

    const int ptBlocks = (tot + TILE_EDGES - 1) / TILE_EDGES;              // 196
    const int prepBlocks = (3 * 16384 + V * 64 + PT_THREADS - 1) / PT_THREADS;
    partprep_kernel<<<ptBlocks + prepBlocks, PT_THREADS, 0, stream>>>(
        A_row, A_col, A_val, E, X_row, X_col, X_val, NNZ,
        nbA, nb, ptBlocks, gcur, ebuf,
        lin1_W, lin2_W, mlp_W, Wt1, Wt2, Wt3,
        (const float2*)emb_W, P_EMB, V * 64);
    cluster2_kernel<<<nb, 1024, 0, stream>>>(
        ebuf, gcur, rsA, reA, rsX, reX, csrA, csrX, nbA, V, D);

    int layer_blocks = (V + 4 * 4 - 1) / (4 * 4);
    layer_kernel<4><<<layer_blocks, 256, 0, stream>>>(
        rsA, reA, csrA, P_EMB, (const float2*)Wt1,
        nullptr, nullptr, nullptr, P_H1, V, 0);
    layer_kernel<4><<<layer_blocks, 256, 0, stream>>>(
        rsA, reA, csrA, P_H1, (const float2*)Wt2,
        (const float2*)emb_W, norm_g, norm_b, P_WS, V, 1);

    int doc_blocks = (D + 4 * 4 - 1) / (4 * 4);
    doc_kernel<4><<<doc_blocks, 256, 0, stream>>>(
        rsX, reX, csrX, P_WS, (const float2*)Wt3,
        mlp_b, clf_W, clf_b, (float*)d_out, D);
}